// Round 23
// baseline (325.055 us; speedup 1.0000x reference)
//
#include <hip/hip_runtime.h>

#define R 256
#define T 32

#define TROWS 16        // out rows per wave tile
#define HC 34           // hidden cols (out cols + halo 1) — EVEN
#define HRR 18          // hidden rows per wave tile
#define HSTR 34         // hidden row stride (words) — UNPADDED: fits 4 blocks/CU
#define CP 612          // plane stride; %32=4 -> cl bank offsets {0,4,8,12}
#define WSLICE (4 * CP) // per-wave hs slice (9792 B)
#define NPX (HRR * HC)  // 612 hidden px per wave tile
#define NPAIR (NPX / 2) // 306 pairs; slots 0..3 full, slot 4: lane < 50

typedef float v2f __attribute__((ext_vector_type(2)));
#define FMA2(a, b, c) __builtin_elementwise_fma((a), (b), (c))

// ---------------------------------------------------------------------------
// Kernel A (R16 verbatim — 512-thr bq-major, yt staged once; ~9 us)
// ---------------------------------------------------------------------------
__global__ __launch_bounds__(512) void einsum_kernel(
    const float* __restrict__ yt, const float* __restrict__ Ht,
    float* __restrict__ x) {
  const int bq  = blockIdx.x >> 6;
  const int yy  = blockIdx.x & 63;
  const int b0  = bq * 8;
  const int tid = threadIdx.x;
  const int q   = tid & 255;
  const int rhh = tid >> 8;
  const int q4  = q >> 2;

  __shared__ float yts[8 * 32 * 64];

#pragma unroll
  for (int i = 0; i < 8; ++i) {
    int f4  = tid + i * 512;
    int b_l = f4 >> 9;
    int t   = (f4 >> 4) & 31;
    int xx4 = f4 & 15;
    float4 v = *(const float4*)(yt + (((size_t)(b0 + b_l) * T + t) * 64 + yy) * 64 + xx4 * 4);
    *(float4*)(yts + f4 * 4) = v;
  }
  __syncthreads();

#pragma unroll
  for (int rr = 0; rr < 2; ++rr) {
    const int p = yy * 4 + rhh * 2 + rr;
    float ht[T];
#pragma unroll
    for (int t = 0; t < T; ++t) ht[t] = Ht[((size_t)t * R + p) * R + q];

#pragma unroll
    for (int b_l = 0; b_l < 8; ++b_l) {
      const float* ys = yts + b_l * 2048 + q4;
      float acc = 0.f;
#pragma unroll
      for (int t = 0; t < T; ++t) acc += ht[t] * ys[t * 64];
      x[((size_t)(b0 + b_l) * R + p) * R + q] = acc;
    }
  }
}

// ---------------------------------------------------------------------------
// Kernel B: fused Conv(1->32,3x3) -> ReLU -> Conv(32->1,3x3), SAME.
// R21 structure; channel-group rotation as a TEMPLATE param (CG0 in {0,4})
// so cg = (CG0+i)&7 folds at compile time — every weight index/LDS offset
// stays an immediate (R22's runtime rotation spilled 94 MB). Even waves run
// phase 0, odd waves phase 4: conv1(VALU) of half the waves overlaps
// conv2(DS) of the other half.
// ---------------------------------------------------------------------------
template <bool EDGE, int CG0>
__device__ __forceinline__ void conv_body(
    const v2f (&patch2)[5][9], bool slot4, const bool (&oob)[10],
    const int (&sw)[5], float* hs,
    const float* __restrict__ W1, const float* __restrict__ b1,
    const float* __restrict__ W2, int cl, int hboff, v2f (&acc2)[8][2]) {
#pragma unroll
  for (int i = 0; i < 8; ++i) {
    const int cg = (CG0 + i) & 7;     // compile-time constant
    float w2[9];
#pragma unroll
    for (int k = 0; k < 9; ++k) w2[k] = W2[(cg * 4 + cl) * 9 + k];

    // ---- conv1 + relu: channels cg*4..cg*4+3 into this wave's 4 planes ----
#pragma unroll
    for (int c = 0; c < 4; ++c) {
      const int ch = cg * 4 + c;      // constant -> s_load weights
      const float bias = b1[ch];
      v2f h[5];
#pragma unroll
      for (int s = 0; s < 5; ++s) h[s] = (v2f){bias, bias};
#pragma unroll
      for (int k = 0; k < 9; ++k) {
        const float w = W1[ch * 9 + k];
        const v2f wv = {w, w};
#pragma unroll
        for (int s = 0; s < 5; ++s) h[s] = FMA2(wv, patch2[s][k], h[s]);
      }
      const v2f z = {0.f, 0.f};
#pragma unroll
      for (int s = 0; s < 5; ++s) h[s] = __builtin_elementwise_max(h[s], z);
      if (EDGE) {
#pragma unroll
        for (int s = 0; s < 5; ++s) {
          if (oob[2 * s])     h[s].x = 0.f;
          if (oob[2 * s + 1]) h[s].y = 0.f;
        }
      }
      float* hp = hs + c * CP;
#pragma unroll
      for (int s = 0; s < 4; ++s) *(v2f*)(hp + sw[s]) = h[s];
      if (slot4) *(v2f*)(hp + sw[4]) = h[4];
    }

    // ---- conv2 partials: 10 rolling rows serve 8 out rows ----
#pragma unroll
    for (int j = 0; j < 10; ++j) {
      const float* hb = hs + hboff + j * HSTR;
      v2f va = *(const v2f*)(hb);        // cols 4g,   4g+1
      v2f vb = *(const v2f*)(hb + 2);    // cols 4g+2, 4g+3
      v2f vc = *(const v2f*)(hb + 4);    // cols 4g+4, 4g+5
      v2f P[5];
      P[0] = va;
      P[1] = (v2f){va.y, vb.x};
      P[2] = vb;
      P[3] = (v2f){vb.y, vc.x};
      P[4] = vc;
#pragma unroll
      for (int dy = 0; dy < 3; ++dy) {
        int ai = j - dy;
        if (ai >= 0 && ai < 8) {
#pragma unroll
          for (int dx = 0; dx < 3; ++dx) {
            const float w = w2[dy * 3 + dx];
            const v2f wv = {w, w};
            acc2[ai][0] = FMA2(wv, P[dx], acc2[ai][0]);
            acc2[ai][1] = FMA2(wv, P[dx + 2], acc2[ai][1]);
          }
        }
      }
    }
  }
}

template <bool EDGE>
__device__ __forceinline__ void conv_tile(
    const float* __restrict__ xb, int ty0, int ox0, int lane, int wv,
    float* hsw,
    const float* __restrict__ W1, const float* __restrict__ b1,
    const float* __restrict__ W2, const float* __restrict__ b2,
    float* __restrict__ outp) {
  v2f  patch2[5][9];
  int  sw[5];
  bool oob[10];
  const bool slot4 = (lane < NPAIR - 4 * 64);   // 50 lanes
#pragma unroll
  for (int it = 0; it < 5; ++it) {
    int pi = lane + it * 64;
    bool act = (it < 4) || slot4;
    int px0 = 2 * pi;
    int hy  = act ? (px0 / HC) : 0;
    int hx0 = act ? (px0 % HC) : 0;       // even
    sw[it] = hy * HSTR + hx0;             // even -> b64-aligned store
    int ghy = ty0 - 1 + hy;
    int ghx0 = ox0 - 1 + hx0;
    bool rowok = (ghy >= 0) & (ghy < R);
    oob[2 * it]     = !(rowok & (ghx0 >= 0) & (ghx0 < R));
    oob[2 * it + 1] = !(rowok & (ghx0 + 1 >= 0) & (ghx0 + 1 < R));
#pragma unroll
    for (int ky = 0; ky < 3; ++ky) {
      const int gy  = ty0 - 2 + hy + ky;
      const int gx0 = ox0 - 2 + hx0;
      v2f fa, fb;
      if (EDGE) {
        float xv[4];
#pragma unroll
        for (int c = 0; c < 4; ++c) {
          int gx = gx0 + c;
          bool ok = act & (gy >= 0) & (gy < R) & (gx >= 0) & (gx < R);
          xv[c] = ok ? xb[gy * R + gx] : 0.f;
        }
        fa = (v2f){xv[0], xv[1]};
        fb = (v2f){xv[2], xv[3]};
      } else {
        const float* xp = xb + gy * R + gx0;
        fa = act ? *(const v2f*)(xp)     : (v2f){0.f, 0.f};
        fb = act ? *(const v2f*)(xp + 2) : (v2f){0.f, 0.f};
      }
      patch2[it][3 * ky + 0] = fa;
      patch2[it][3 * ky + 1] = (v2f){fa.y, fb.x};
      patch2[it][3 * ky + 2] = fb;
    }
  }

  const int g  = lane & 7;          // col granule: px 4g..4g+3
  const int cl = (lane >> 3) & 3;   // channel in group
  const int rh = lane >> 5;         // 0..1: out rows 8rh..8rh+7
  const int r0 = 8 * rh;

  v2f acc2[8][2];
#pragma unroll
  for (int ai = 0; ai < 8; ++ai) {
    acc2[ai][0] = (v2f){0.f, 0.f};
    acc2[ai][1] = (v2f){0.f, 0.f};
  }

  const int hboff = cl * CP + r0 * HSTR + 4 * g;

  if (wv & 1)
    conv_body<EDGE, 4>(patch2, slot4, oob, sw, hsw, W1, b1, W2, cl, hboff, acc2);
  else
    conv_body<EDGE, 0>(patch2, slot4, oob, sw, hsw, W1, b1, W2, cl, hboff, acc2);

  const float bias2 = b2[0];
#pragma unroll
  for (int ai = 0; ai < 8; ++ai)
#pragma unroll
    for (int h = 0; h < 2; ++h) {
      float vx = acc2[ai][h].x, vy = acc2[ai][h].y;
      vx += __shfl_xor(vx, 8);  vy += __shfl_xor(vy, 8);
      vx += __shfl_xor(vx, 16); vy += __shfl_xor(vy, 16);
      acc2[ai][h].x = vx; acc2[ai][h].y = vy;
    }
  if (cl == 0) {
#pragma unroll
    for (int ai = 0; ai < 8; ++ai) {
      float4 o = {acc2[ai][0].x + bias2, acc2[ai][0].y + bias2,
                  acc2[ai][1].x + bias2, acc2[ai][1].y + bias2};
      *(float4*)(outp + (ty0 + r0 + ai) * R + ox0 + 4 * g) = o;
    }
  }
}

__global__ __launch_bounds__(256) void conv_fused_kernel(
    const float* __restrict__ x, const float* __restrict__ W1,
    const float* __restrict__ b1, const float* __restrict__ W2,
    const float* __restrict__ b2, float* __restrict__ out) {
  __shared__ float hs[4 * WSLICE];   // 39168 B -> 4 blocks/CU

  const int tid  = threadIdx.x;
  const int lane = tid & 63;
  const int wv   = tid >> 6;
  const int b    = blockIdx.x >> 5;
  const int tile = blockIdx.x & 31;          // 4 row-blocks x 8 col-blocks
  const int ty0  = (tile >> 3) * 64 + wv * TROWS;
  const int ox0  = (tile & 7) * 32;
  const float* xb   = x + (size_t)b * R * R;
  float*       outp = out + (size_t)b * R * R;
  float*       hsw  = hs + wv * WSLICE;

  const bool edge = (ty0 == 0) | (ty0 == R - TROWS) | (ox0 == 0) | (ox0 == R - 32);
  if (edge)
    conv_tile<true>(xb, ty0, ox0, lane, wv, hsw, W1, b1, W2, b2, outp);
  else
    conv_tile<false>(xb, ty0, ox0, lane, wv, hsw, W1, b1, W2, b2, outp);
}

// ---------------------------------------------------------------------------
extern "C" void kernel_launch(void* const* d_in, const int* in_sizes, int n_in,
                              void* d_out, int out_size, void* d_ws, size_t ws_size,
                              hipStream_t stream) {
  const float* yt = (const float*)d_in[0];  // (32,32,64,64)
  const float* Ht = (const float*)d_in[1];  // (32,256,256)
  const float* W1 = (const float*)d_in[2];  // (32,1,3,3)
  const float* b1 = (const float*)d_in[3];  // (32,)
  const float* W2 = (const float*)d_in[4];  // (1,32,3,3)
  const float* b2 = (const float*)d_in[5];  // (1,)
  float* outp = (float*)d_out;              // (32,1,256,256)
  float* x    = (float*)d_ws;               // 8 MB scratch

  einsum_kernel<<<256, 512, 0, stream>>>(yt, Ht, x);
  conv_fused_kernel<<<1024, 256, 0, stream>>>(x, W1, b1, W2, b2, outp);
}

// Round 24
// 121.678 us; speedup vs baseline: 2.6715x; 2.6715x over previous
//
#include <hip/hip_runtime.h>

#define R 256
#define T 32

#define TROWS 16        // out rows per wave tile
#define HC 34           // hidden cols (out cols + halo 1) — EVEN
#define HRR 18          // hidden rows per wave tile
#define HSTR 34         // hidden row stride (words) — UNPADDED: fits 4 blocks/CU
#define CP 612          // plane stride; %32=4 -> cl bank offsets {0,4,8,12}
#define WSLICE (4 * CP) // per-wave hs slice (9792 B)
#define NPX (HRR * HC)  // 612 hidden px per wave tile
#define NPAIR (NPX / 2) // 306 pairs; slots 0..3 full, slot 4: lane < 50

typedef float v2f __attribute__((ext_vector_type(2)));
#define FMA2(a, b, c) __builtin_elementwise_fma((a), (b), (c))

// ---------------------------------------------------------------------------
// Kernel A (R16 — 512-thr bq-major, yt staged once; ~9 us)
// ---------------------------------------------------------------------------
__global__ __launch_bounds__(512) void einsum_kernel(
    const float* __restrict__ yt, const float* __restrict__ Ht,
    float* __restrict__ x) {
  const int bq  = blockIdx.x >> 6;
  const int yy  = blockIdx.x & 63;
  const int b0  = bq * 8;
  const int tid = threadIdx.x;
  const int q   = tid & 255;
  const int rhh = tid >> 8;
  const int q4  = q >> 2;

  __shared__ float yts[8 * 32 * 64];

#pragma unroll
  for (int i = 0; i < 8; ++i) {
    int f4  = tid + i * 512;
    int b_l = f4 >> 9;
    int t   = (f4 >> 4) & 31;
    int xx4 = f4 & 15;
    float4 v = *(const float4*)(yt + (((size_t)(b0 + b_l) * T + t) * 64 + yy) * 64 + xx4 * 4);
    *(float4*)(yts + f4 * 4) = v;
  }
  __syncthreads();

#pragma unroll
  for (int rr = 0; rr < 2; ++rr) {
    const int p = yy * 4 + rhh * 2 + rr;
    float ht[T];
#pragma unroll
    for (int t = 0; t < T; ++t) ht[t] = Ht[((size_t)t * R + p) * R + q];

#pragma unroll
    for (int b_l = 0; b_l < 8; ++b_l) {
      const float* ys = yts + b_l * 2048 + q4;
      float acc = 0.f;
#pragma unroll
      for (int t = 0; t < T; ++t) acc += ht[t] * ys[t * 64];
      x[((size_t)(b0 + b_l) * R + p) * R + q] = acc;
    }
  }
}

// ---------------------------------------------------------------------------
// Kernel B (R21 verbatim — best known: 46.6 us):
// fused Conv(1->32,3x3) -> ReLU -> Conv(32->1,3x3), SAME.
// 16x32 wave-private tiles, packed fp32 (v_pk_fma), contiguous px pairs,
// no barriers, unpadded HSTR=34 -> 39168 B block LDS -> 4 blocks/CU (whole
// 1024-block grid co-resident). Single static body: any runtime cg rotation
// or dual-body branching spills catastrophically (R22/R23: VGPR 256,
// ~100 MB scratch). Keep every index compile-time constant.
// ---------------------------------------------------------------------------
template <bool EDGE>
__device__ __forceinline__ void conv_body(
    const v2f (&patch2)[5][9], bool slot4, const bool (&oob)[10],
    const int (&sw)[5], float* hs,
    const float* __restrict__ W1, const float* __restrict__ b1,
    const float* __restrict__ W2, int cl, int hboff, v2f (&acc2)[8][2]) {
  for (int cg = 0; cg < 8; ++cg) {
    float w2[9];
#pragma unroll
    for (int k = 0; k < 9; ++k) w2[k] = W2[(cg * 4 + cl) * 9 + k];

    // ---- conv1 + relu: channels cg*4..cg*4+3 into this wave's 4 planes ----
#pragma unroll
    for (int c = 0; c < 4; ++c) {
      const int ch = cg * 4 + c;
      const float bias = b1[ch];
      v2f h[5];
#pragma unroll
      for (int s = 0; s < 5; ++s) h[s] = (v2f){bias, bias};
#pragma unroll
      for (int k = 0; k < 9; ++k) {
        const float w = W1[ch * 9 + k];
        const v2f wv = {w, w};
#pragma unroll
        for (int s = 0; s < 5; ++s) h[s] = FMA2(wv, patch2[s][k], h[s]);
      }
      const v2f z = {0.f, 0.f};
#pragma unroll
      for (int s = 0; s < 5; ++s) h[s] = __builtin_elementwise_max(h[s], z);
      if (EDGE) {
#pragma unroll
        for (int s = 0; s < 5; ++s) {
          if (oob[2 * s])     h[s].x = 0.f;
          if (oob[2 * s + 1]) h[s].y = 0.f;
        }
      }
      float* hp = hs + c * CP;
#pragma unroll
      for (int s = 0; s < 4; ++s) *(v2f*)(hp + sw[s]) = h[s];
      if (slot4) *(v2f*)(hp + sw[4]) = h[4];
    }

    // ---- conv2 partials: 10 rolling rows serve 8 out rows ----
#pragma unroll
    for (int j = 0; j < 10; ++j) {
      const float* hb = hs + hboff + j * HSTR;
      v2f va = *(const v2f*)(hb);        // cols 4g,   4g+1
      v2f vb = *(const v2f*)(hb + 2);    // cols 4g+2, 4g+3
      v2f vc = *(const v2f*)(hb + 4);    // cols 4g+4, 4g+5
      v2f P[5];
      P[0] = va;
      P[1] = (v2f){va.y, vb.x};
      P[2] = vb;
      P[3] = (v2f){vb.y, vc.x};
      P[4] = vc;
#pragma unroll
      for (int dy = 0; dy < 3; ++dy) {
        int ai = j - dy;
        if (ai >= 0 && ai < 8) {
#pragma unroll
          for (int dx = 0; dx < 3; ++dx) {
            const float w = w2[dy * 3 + dx];
            const v2f wv = {w, w};
            acc2[ai][0] = FMA2(wv, P[dx], acc2[ai][0]);
            acc2[ai][1] = FMA2(wv, P[dx + 2], acc2[ai][1]);
          }
        }
      }
    }
  }
}

template <bool EDGE>
__device__ __forceinline__ void conv_tile(
    const float* __restrict__ xb, int ty0, int ox0, int lane, float* hsw,
    const float* __restrict__ W1, const float* __restrict__ b1,
    const float* __restrict__ W2, const float* __restrict__ b2,
    float* __restrict__ outp) {
  v2f  patch2[5][9];
  int  sw[5];
  bool oob[10];
  const bool slot4 = (lane < NPAIR - 4 * 64);   // 50 lanes
#pragma unroll
  for (int it = 0; it < 5; ++it) {
    int pi = lane + it * 64;
    bool act = (it < 4) || slot4;
    int px0 = 2 * pi;
    int hy  = act ? (px0 / HC) : 0;
    int hx0 = act ? (px0 % HC) : 0;       // even
    sw[it] = hy * HSTR + hx0;             // even -> b64-aligned store
    int ghy = ty0 - 1 + hy;
    int ghx0 = ox0 - 1 + hx0;
    bool rowok = (ghy >= 0) & (ghy < R);
    oob[2 * it]     = !(rowok & (ghx0 >= 0) & (ghx0 < R));
    oob[2 * it + 1] = !(rowok & (ghx0 + 1 >= 0) & (ghx0 + 1 < R));
#pragma unroll
    for (int ky = 0; ky < 3; ++ky) {
      const int gy  = ty0 - 2 + hy + ky;
      const int gx0 = ox0 - 2 + hx0;
      v2f fa, fb;
      if (EDGE) {
        float xv[4];
#pragma unroll
        for (int c = 0; c < 4; ++c) {
          int gx = gx0 + c;
          bool ok = act & (gy >= 0) & (gy < R) & (gx >= 0) & (gx < R);
          xv[c] = ok ? xb[gy * R + gx] : 0.f;
        }
        fa = (v2f){xv[0], xv[1]};
        fb = (v2f){xv[2], xv[3]};
      } else {
        const float* xp = xb + gy * R + gx0;
        fa = act ? *(const v2f*)(xp)     : (v2f){0.f, 0.f};
        fb = act ? *(const v2f*)(xp + 2) : (v2f){0.f, 0.f};
      }
      patch2[it][3 * ky + 0] = fa;
      patch2[it][3 * ky + 1] = (v2f){fa.y, fb.x};
      patch2[it][3 * ky + 2] = fb;
    }
  }

  const int g  = lane & 7;          // col granule: px 4g..4g+3
  const int cl = (lane >> 3) & 3;   // channel in group
  const int rh = lane >> 5;         // 0..1: out rows 8rh..8rh+7
  const int r0 = 8 * rh;

  v2f acc2[8][2];
#pragma unroll
  for (int ai = 0; ai < 8; ++ai) {
    acc2[ai][0] = (v2f){0.f, 0.f};
    acc2[ai][1] = (v2f){0.f, 0.f};
  }

  const int hboff = cl * CP + r0 * HSTR + 4 * g;

  conv_body<EDGE>(patch2, slot4, oob, sw, hsw, W1, b1, W2, cl, hboff, acc2);

  const float bias2 = b2[0];
#pragma unroll
  for (int ai = 0; ai < 8; ++ai)
#pragma unroll
    for (int h = 0; h < 2; ++h) {
      float vx = acc2[ai][h].x, vy = acc2[ai][h].y;
      vx += __shfl_xor(vx, 8);  vy += __shfl_xor(vy, 8);
      vx += __shfl_xor(vx, 16); vy += __shfl_xor(vy, 16);
      acc2[ai][h].x = vx; acc2[ai][h].y = vy;
    }
  if (cl == 0) {
#pragma unroll
    for (int ai = 0; ai < 8; ++ai) {
      float4 o = {acc2[ai][0].x + bias2, acc2[ai][0].y + bias2,
                  acc2[ai][1].x + bias2, acc2[ai][1].y + bias2};
      *(float4*)(outp + (ty0 + r0 + ai) * R + ox0 + 4 * g) = o;
    }
  }
}

__global__ __launch_bounds__(256) void conv_fused_kernel(
    const float* __restrict__ x, const float* __restrict__ W1,
    const float* __restrict__ b1, const float* __restrict__ W2,
    const float* __restrict__ b2, float* __restrict__ out) {
  __shared__ float hs[4 * WSLICE];   // 39168 B -> 4 blocks/CU

  const int tid  = threadIdx.x;
  const int lane = tid & 63;
  const int wv   = tid >> 6;
  const int b    = blockIdx.x >> 5;
  const int tile = blockIdx.x & 31;          // 4 row-blocks x 8 col-blocks
  const int ty0  = (tile >> 3) * 64 + wv * TROWS;
  const int ox0  = (tile & 7) * 32;
  const float* xb   = x + (size_t)b * R * R;
  float*       outp = out + (size_t)b * R * R;
  float*       hsw  = hs + wv * WSLICE;

  const bool edge = (ty0 == 0) | (ty0 == R - TROWS) | (ox0 == 0) | (ox0 == R - 32);
  if (edge)
    conv_tile<true>(xb, ty0, ox0, lane, hsw, W1, b1, W2, b2, outp);
  else
    conv_tile<false>(xb, ty0, ox0, lane, hsw, W1, b1, W2, b2, outp);
}

// ---------------------------------------------------------------------------
extern "C" void kernel_launch(void* const* d_in, const int* in_sizes, int n_in,
                              void* d_out, int out_size, void* d_ws, size_t ws_size,
                              hipStream_t stream) {
  const float* yt = (const float*)d_in[0];  // (32,32,64,64)
  const float* Ht = (const float*)d_in[1];  // (32,256,256)
  const float* W1 = (const float*)d_in[2];  // (32,1,3,3)
  const float* b1 = (const float*)d_in[3];  // (32,)
  const float* W2 = (const float*)d_in[4];  // (1,32,3,3)
  const float* b2 = (const float*)d_in[5];  // (1,)
  float* outp = (float*)d_out;              // (32,1,256,256)
  float* x    = (float*)d_ws;               // 8 MB scratch

  einsum_kernel<<<256, 512, 0, stream>>>(yt, Ht, x);
  conv_fused_kernel<<<1024, 256, 0, stream>>>(x, W1, b1, W2, b2, outp);
}